// Round 3
// baseline (584.687 us; speedup 1.0000x reference)
//
#include <hip/hip_runtime.h>
#include <stdint.h>
#include <math.h>

#define M_DIM 8192
#define N_DIM 4096
#define K_DIM 4096
#define BITWIDTH 7

#define BM 256
#define BN 128
#define BK 128   // bytes of K per tile (row stride in LDS for B)

using i32x4  = __attribute__((ext_vector_type(4)))  int;
using i32x16 = __attribute__((ext_vector_type(16))) int;

// ---------------------------------------------------------------------------
// Fused pack: int32 (int8-range values) -> int8 for BOTH tensors, one launch.
// 8 elements (32B read, 8B write) per thread, block-aligned split.
// Also zero-inits the maxabs scalar (replaces a memset dispatch).
// ---------------------------------------------------------------------------
__global__ __launch_bounds__(256) void pack_both_kernel(
        const int* __restrict__ act, const int* __restrict__ wt,
        uint32_t* __restrict__ act8, uint32_t* __restrict__ w8,
        int* __restrict__ maxabs) {
    if (blockIdx.x == 0 && threadIdx.x == 0) *maxabs = 0;
    const int ACT_N8 = (M_DIM * K_DIM) / 8;   // 4194304
    int i = blockIdx.x * blockDim.x + threadIdx.x;
    const int* src;
    uint32_t* dst;
    if (i < ACT_N8) { src = act; dst = act8; }
    else            { src = wt;  dst = w8;  i -= ACT_N8; }
    int4 a = ((const int4*)src)[2 * i];
    int4 b = ((const int4*)src)[2 * i + 1];
    uint32_t p0 = (uint32_t)(a.x & 0xFF) | ((uint32_t)(a.y & 0xFF) << 8)
                | ((uint32_t)(a.z & 0xFF) << 16) | ((uint32_t)(a.w & 0xFF) << 24);
    uint32_t p1 = (uint32_t)(b.x & 0xFF) | ((uint32_t)(b.y & 0xFF) << 8)
                | ((uint32_t)(b.z & 0xFF) << 16) | ((uint32_t)(b.w & 0xFF) << 24);
    ((uint2*)dst)[i] = make_uint2(p0, p1);
}

// ---------------------------------------------------------------------------
// async global->LDS, 16B per lane, LDS dest = wave-uniform base + lane*16
// ---------------------------------------------------------------------------
__device__ __forceinline__ void gload_lds16(const int8_t* g, int8_t* lds) {
    __builtin_amdgcn_global_load_lds(
        (__attribute__((address_space(1))) void*)g,
        (__attribute__((address_space(3))) void*)lds,
        16, 0, 0);
}

// ---------------------------------------------------------------------------
// i8 GEMM: C[m][n] = sum_k A8[m][k] * B8[n][k]   (B given transposed)
//
// R2 structure (resubmit after infra failure): A fragments read DIRECTLY
// from global (VMEM/L1 pipe); only B is LDS-staged (2-slot ring, 32 KB).
// Rationale (R0/R1 counters): the 128x64 wave tile demands 84 B/cyc of
// LDS read per MFMA-cycle -- at the 85 B/cyc ds_read_b128 ceiling BEFORE
// the ~4-way bank-conflict floor (rows fr and fr+8 always alias for
// 128B-multiple row strides). Moving A (2/3 of LDS reads) to the VMEM
// pipe drops LDS demand to ~55% of MFMA time; the A tile (32 KB) is
// exactly L1-sized and L2-panel-backed under the default grid mapping.
//
// Single __syncthreads per K-tile: ring-2 + stage-at-top means writes to
// slot s in iter t and reads of slot s in iter t+1 are separated by the
// iter-t barrier; the B(t+1) gloads it drains were issued before the full
// MFMA phase, so their latency is hidden under compute.
// ---------------------------------------------------------------------------
__global__ __launch_bounds__(256, 2) void gemm_i8(
        const int8_t* __restrict__ A8, const int8_t* __restrict__ B8,
        int* __restrict__ C, int* __restrict__ maxabs) {
    __shared__ __align__(16) int8_t Bs[2][BN * BK];   // 2 x 16 KB ring
    __shared__ int wmaxs[4];

    const int tid  = threadIdx.x;
    const int wave = tid >> 6;
    const int lane = tid & 63;
    const int fr   = lane & 31;
    const int hl   = lane >> 5;

    const int row0 = blockIdx.y * BM;
    const int col0 = blockIdx.x * BN;

    const int wm = (wave >> 1) * 128;  // wave row offset in block tile
    const int wn = (wave & 1) * 64;    // wave col offset

    i32x16 acc[4][2];
#pragma unroll
    for (int i = 0; i < 4; ++i)
#pragma unroll
        for (int j = 0; j < 2; ++j)
            acc[i][j] = (i32x16)(0);

    // --- B staging addressing ----------------------------------------------
    // Round g (0..3), wave w, lane L: element e = g*256 + w*64 + L covers
    // LDS row g*32 + w*8 + (L>>3), slot L&7. Source chunk pre-swizzled:
    // (L&7) ^ (row&7), row&7 = (L>>3). LDS dest: linear, base + lane*16.
    const int srowoff = lane >> 3;                        // 0..7
    const int schk    = ((lane & 7) ^ srowoff) << 4;      // swizzled src chunk
    const int8_t* bg  = B8 + (size_t)(col0 + wave * 8 + srowoff) * K_DIM + schk;
    const int ldsoB   = wave * 1024;                      // within a round

    // --- A fragment addressing (global-direct) ------------------------------
    // 32x32x32 i8 A fragment: row = lane&31, k-bytes = kk*32 + hl*16 + 0..15.
    // Per-lane base pointer; loop adds row-block and k offsets.
    const int8_t* agf = A8 + (size_t)(row0 + wm + fr) * K_DIM + hl * 16;

    // --- B fragment LDS offsets (loop-invariant) ----------------------------
    // B frag row = wn + j*32 + fr, chunk c = kk*2 + hl, slot = c ^ (row&7).
    const int swz = fr & 7;
    int boff[4][2];
#pragma unroll
    for (int kk = 0; kk < 4; ++kk) {
        const int co = (((kk * 2 + hl) ^ swz) << 4);
#pragma unroll
        for (int j = 0; j < 2; ++j)
            boff[kk][j] = (wn + j * 32 + fr) * BK + co;
    }

    // --- prologue: stage B tile 0 into slot 0 ------------------------------
#pragma unroll
    for (int g = 0; g < 4; ++g)
        gload_lds16(bg + (size_t)(32 * g) * K_DIM, Bs[0] + g * 4096 + ldsoB);
    __syncthreads();

    // --- main K loop: one barrier per tile ---------------------------------
    for (int t = 0; t < K_DIM / BK; ++t) {
        const int k0  = t * BK;
        const int buf = t & 1;

        // stage B(t+1) into the other slot (write-vs-read separated by the
        // barrier at the END of this iteration / start of next reads)
        if (t < K_DIM / BK - 1) {
#pragma unroll
            for (int g = 0; g < 4; ++g)
                gload_lds16(bg + k0 + BK + (size_t)(32 * g) * K_DIM,
                            Bs[buf ^ 1] + g * 4096 + ldsoB);
        }

#pragma unroll
        for (int kk = 0; kk < 4; ++kk) {
            i32x4 af[4], bf[2];
#pragma unroll
            for (int i = 0; i < 4; ++i)
                af[i] = *(const i32x4*)(agf + (size_t)(i * 32) * K_DIM
                                            + k0 + kk * 32);
#pragma unroll
            for (int j = 0; j < 2; ++j)
                bf[j] = *(const i32x4*)(Bs[buf] + boff[kk][j]);
#pragma unroll
            for (int i = 0; i < 4; ++i)
#pragma unroll
                for (int j = 0; j < 2; ++j)
                    acc[i][j] = __builtin_amdgcn_mfma_i32_32x32x32_i8(
                        af[i], bf[j], acc[i][j], 0, 0, 0);
        }
        __syncthreads();   // drains B(t+1) gloads (hidden) + slot-flip guard
    }

    // epilogue: 32x32 C/D layout: col = lane&31,
    // row = (reg&3) + 8*(reg>>2) + 4*(lane>>5)   [m74/m101, dtype-independent]
    int mymax = 0;
    const int ccol = fr;
    const int rbase = hl << 2;
#pragma unroll
    for (int i = 0; i < 4; ++i) {
#pragma unroll
        for (int j = 0; j < 2; ++j) {
            int* p = C + (size_t)(row0 + wm + i * 32) * N_DIM
                       + (col0 + wn + j * 32 + ccol);
#pragma unroll
            for (int r = 0; r < 16; ++r) {
                int row = (r & 3) + 8 * (r >> 2) + rbase;
                int v = acc[i][j][r];
                p[(size_t)row * N_DIM] = v;
                int a = v < 0 ? -v : v;
                mymax = a > mymax ? a : mymax;
            }
        }
    }

    // wave-reduce max, then one atomic per block
#pragma unroll
    for (int off = 32; off > 0; off >>= 1) {
        int o = __shfl_down(mymax, off, 64);
        mymax = o > mymax ? o : mymax;
    }
    if (lane == 0) wmaxs[wave] = mymax;
    __syncthreads();
    if (tid == 0) {
        int bmx = wmaxs[0];
        for (int w = 1; w < 4; ++w) bmx = wmaxs[w] > bmx ? wmaxs[w] : bmx;
        atomicMax(maxabs, bmx);
    }
}

// ---------------------------------------------------------------------------
// Pseudo-stochastic shift, faithful to PstoShiftInt32 (all-integer, exact).
// Returns the int8 result sign-extended to int32.
// ---------------------------------------------------------------------------
__device__ __forceinline__ int psto(int x, int eff) {
    if (eff > 0) {
        int rt   = x >> eff;                 // floor divide by 2^eff
        int prob = x & ((1 << eff) - 1);     // non-negative floor remainder
        int h    = eff >> 1;
        int qp   = prob >> h;
        int prn  = (prob & ((1 << h) - 1)) << (eff & 1);
        int sgn  = (x > 0) - (x < 0);
        int r    = rt + ((qp <= prn) ? 0 : sgn);
        r = r < -127 ? -127 : r;
        r = r > 127 ? 127 : r;
        return r;
    }
    return (int)(int8_t)x;                   // wrapping int8 cast, as in torch
}

// ---------------------------------------------------------------------------
// In-place: read int32 acc from C, write int32 quantized value back.
// 8 elements (two int4) per thread. d_out is an int32 buffer.
// ---------------------------------------------------------------------------
__global__ __launch_bounds__(256) void finalize_kernel(int* __restrict__ C,
        const int* __restrict__ maxabs,
        const int* __restrict__ exp_in,
        const int* __restrict__ wexp) {
    const int m = *maxabs;
    int bw = 0;
    if (m != 0) bw = (int)ceilf(log2f((float)m));   // float32 path, as reference
    const int shift = bw - BITWIDTH;
    const int eff = (shift > 1) ? shift : ((shift == 1) ? 2 : 0);

    const size_t idx = ((size_t)blockIdx.x * blockDim.x + threadIdx.x) * 8;
    int4 v0 = *(const int4*)(C + idx);
    int4 v1 = *(const int4*)(C + idx + 4);
    int4 o0, o1;
    o0.x = psto(v0.x, eff); o0.y = psto(v0.y, eff);
    o0.z = psto(v0.z, eff); o0.w = psto(v0.w, eff);
    o1.x = psto(v1.x, eff); o1.y = psto(v1.y, eff);
    o1.z = psto(v1.z, eff); o1.w = psto(v1.w, eff);
    *(int4*)(C + idx) = o0;
    *(int4*)(C + idx + 4) = o1;

    if (idx == 0) {
        C[(size_t)M_DIM * N_DIM] = (int)(int8_t)(exp_in[0] + wexp[0] + eff);
    }
}

// ---------------------------------------------------------------------------
extern "C" void kernel_launch(void* const* d_in, const int* in_sizes, int n_in,
                              void* d_out, int out_size, void* d_ws, size_t ws_size,
                              hipStream_t stream) {
    const int* act    = (const int*)d_in[0];
    const int* exp_in = (const int*)d_in[1];
    const int* wt     = (const int*)d_in[2];
    const int* wexp   = (const int*)d_in[3];

    int8_t* act8   = (int8_t*)d_ws;                          // 32 MB
    int8_t* w8     = act8 + (size_t)M_DIM * K_DIM;           // 16 MB
    int*    maxabs = (int*)(w8 + (size_t)N_DIM * K_DIM);     // 4 B

    // 8 elem/thread over act (16384 blocks) then weight (8192 blocks).
    pack_both_kernel<<<24576, 256, 0, stream>>>(
        act, wt, (uint32_t*)act8, (uint32_t*)w8, maxabs);

    int* C = (int*)d_out;    // acc staged in-place in d_out
    dim3 grid(N_DIM / BN, M_DIM / BM);
    gemm_i8<<<grid, 256, 0, stream>>>(act8, w8, C, maxabs);

    finalize_kernel<<<((size_t)M_DIM * N_DIM / 8) / 256, 256, 0, stream>>>(
        C, maxabs, exp_in, wexp);
}

// Round 4
// 451.094 us; speedup vs baseline: 1.2962x; 1.2962x over previous
//
#include <hip/hip_runtime.h>
#include <stdint.h>
#include <math.h>

#define M_DIM 8192
#define N_DIM 4096
#define K_DIM 4096
#define BITWIDTH 7

#define BM 256
#define BN 128
#define BK 128   // bytes of K per tile (row stride in LDS for B)

using i32x4  = __attribute__((ext_vector_type(4)))  int;
using i32x16 = __attribute__((ext_vector_type(16))) int;

// ---------------------------------------------------------------------------
// Combined pack, one launch:
//   blocks [0, 8192):    A -> MFMA-fragment-blocked int8 layout
//   blocks [8192,16384): B -> row-major int8 (unchanged path)
//
// A packed layout: for M-block mb (32 rows) and K-block kb (32 bytes), a
// 1 KB block at ((mb*128 + kb) * 1024) holding lane L's 16 fragment bytes
// at offset L*16: A[mb*32 + (L&31)][kb*32 + (L>>5)*16 + 0..15]. This is
// byte-identical to the LDS image R0's (verified-correct) fragment reads
// consumed, so gemm A-loads become coalesced global_load_dwordx4.
// Source reads: 16 consecutive int32 (64B) per thread; a wave covers 32
// rows x 128B contiguous-per-row -> cache-line granular. Writes: tid*16,
// perfectly coalesced.
// ---------------------------------------------------------------------------
__global__ __launch_bounds__(256) void pack_both_kernel(
        const int* __restrict__ act, const int* __restrict__ wt,
        uint32_t* __restrict__ a8p, uint32_t* __restrict__ w8,
        int* __restrict__ maxabs) {
    if (blockIdx.x == 0 && threadIdx.x == 0) *maxabs = 0;

    if (blockIdx.x < 8192) {
        // ---- A fragment pack: 2,097,152 threads, 16B out each ----
        const int tid = blockIdx.x * 256 + threadIdx.x;
        const int L  = tid & 63;
        const int kb = (tid >> 6) & 127;          // K/32 = 128 blocks
        const int mb = tid >> 13;                 // M/32 = 256 blocks
        const size_t src = (size_t)(mb * 32 + (L & 31)) * K_DIM
                         + kb * 32 + (L >> 5) * 16;
        const int4* s = (const int4*)(act + src);
        uint32_t w[4];
#pragma unroll
        for (int q = 0; q < 4; ++q) {
            int4 v = s[q];
            w[q] = (uint32_t)(v.x & 0xFF) | ((uint32_t)(v.y & 0xFF) << 8)
                 | ((uint32_t)(v.z & 0xFF) << 16) | ((uint32_t)(v.w & 0xFF) << 24);
        }
        ((uint4*)a8p)[tid] = make_uint4(w[0], w[1], w[2], w[3]);
    } else {
        // ---- B row-major pack: 8 int32 -> 8 bytes per thread ----
        const int i = (blockIdx.x - 8192) * 256 + threadIdx.x;
        int4 a = ((const int4*)wt)[2 * i];
        int4 b = ((const int4*)wt)[2 * i + 1];
        uint32_t p0 = (uint32_t)(a.x & 0xFF) | ((uint32_t)(a.y & 0xFF) << 8)
                    | ((uint32_t)(a.z & 0xFF) << 16) | ((uint32_t)(a.w & 0xFF) << 24);
        uint32_t p1 = (uint32_t)(b.x & 0xFF) | ((uint32_t)(b.y & 0xFF) << 8)
                    | ((uint32_t)(b.z & 0xFF) << 16) | ((uint32_t)(b.w & 0xFF) << 24);
        ((uint2*)w8)[i] = make_uint2(p0, p1);
    }
}

// ---------------------------------------------------------------------------
// async global->LDS, 16B per lane, LDS dest = wave-uniform base + lane*16
// ---------------------------------------------------------------------------
__device__ __forceinline__ void gload_lds16(const int8_t* g, int8_t* lds) {
    __builtin_amdgcn_global_load_lds(
        (__attribute__((address_space(1))) void*)g,
        (__attribute__((address_space(3))) void*)lds,
        16, 0, 0);
}

// ---------------------------------------------------------------------------
// i8 GEMM: C[m][n] = sum_k A8[m][k] * B8[n][k]   (B given transposed)
//
// R4 structure: A fragments loaded DIRECTLY from the fragment-packed
// global layout (coalesced dwordx4, lane L at base+L*16, L1/L2-served);
// B staged in LDS exactly as R0 (single 16 KB buffer, XOR swizzle,
// global_load_lds, 2 barriers per K-tile). Per-CU budget moves from
// {MFMA 62, LDS 101} serialized (=R0's 159us) to
// {MFMA 62, LDS-B ~34, VMEM-A ~30-55} on three separate pipes.
// ---------------------------------------------------------------------------
__global__ __launch_bounds__(256, 2) void gemm_i8(
        const int8_t* __restrict__ A8p, const int8_t* __restrict__ B8,
        int* __restrict__ C, int* __restrict__ maxabs) {
    __shared__ __align__(16) int8_t Bs[BN * BK];   // 16 KB, single buffer
    __shared__ int wmaxs[4];

    const int tid  = threadIdx.x;
    const int wave = tid >> 6;
    const int lane = tid & 63;
    const int fr   = lane & 31;
    const int hl   = lane >> 5;

    const int row0 = blockIdx.y * BM;
    const int col0 = blockIdx.x * BN;

    const int wm = (wave >> 1) * 128;  // wave row offset in block tile
    const int wn = (wave & 1) * 64;    // wave col offset

    i32x16 acc[4][2];
#pragma unroll
    for (int i = 0; i < 4; ++i)
#pragma unroll
        for (int j = 0; j < 2; ++j)
            acc[i][j] = (i32x16)(0);

    // --- B staging addressing (R0-verified) ---------------------------------
    // Round g (0..3), wave w, lane L: LDS row 32g + w*8 + (L>>3), slot L&7;
    // source chunk pre-swizzled (L&7)^(row&7). LDS dest linear.
    const int srowoff = lane >> 3;
    const int schk    = ((lane & 7) ^ srowoff) << 4;
    const int8_t* bg  = B8 + (size_t)(col0 + wave * 8 + srowoff) * K_DIM + schk;
    const int ldsoB   = wave * 1024;

    // --- A fragment addressing (packed global, coalesced) -------------------
    // Fragment (i-block, kb): 1 KB block at ((mbase+i)*128 + kb)*1024,
    // lane offset L*16. kb = t*4 + kk.
    const int mbase = (row0 + wm) >> 5;
    const int8_t* aBase = A8p + (size_t)mbase * 128 * 1024 + (size_t)lane * 16;

    // --- B fragment LDS offsets (loop-invariant, R0-verified) ---------------
    const int swz = fr & 7;
    int boff[4][2];
#pragma unroll
    for (int kk = 0; kk < 4; ++kk) {
        const int co = (((kk * 2 + hl) ^ swz) << 4);
#pragma unroll
        for (int j = 0; j < 2; ++j)
            boff[kk][j] = (wn + j * 32 + fr) * BK + co;
    }

    for (int t = 0; t < K_DIM / BK; ++t) {
        const int k0 = t * BK;
        __syncthreads();   // protect Bs from previous iteration's readers
#pragma unroll
        for (int g = 0; g < 4; ++g)
            gload_lds16(bg + k0 + (size_t)(32 * g) * K_DIM,
                        Bs + g * 4096 + ldsoB);

        // issue all 16 A-fragment loads for this tile (registers)
        i32x4 af[16];
#pragma unroll
        for (int i = 0; i < 4; ++i)
#pragma unroll
            for (int kk = 0; kk < 4; ++kk)
                af[i * 4 + kk] = *(const i32x4*)(aBase
                    + (size_t)(i * 128 + t * 4 + kk) * 1024);

        __syncthreads();   // vmcnt(0) drain: B in LDS, af in regs

#pragma unroll
        for (int kk = 0; kk < 4; ++kk) {
            i32x4 bf[2];
#pragma unroll
            for (int j = 0; j < 2; ++j)
                bf[j] = *(const i32x4*)(Bs + boff[kk][j]);
#pragma unroll
            for (int i = 0; i < 4; ++i)
#pragma unroll
                for (int j = 0; j < 2; ++j)
                    acc[i][j] = __builtin_amdgcn_mfma_i32_32x32x32_i8(
                        af[i * 4 + kk], bf[j], acc[i][j], 0, 0, 0);
        }
    }

    // epilogue: 32x32 C/D layout: col = lane&31,
    // row = (reg&3) + 8*(reg>>2) + 4*(lane>>5)   [m74/m101, dtype-independent]
    int mymax = 0;
    const int ccol = fr;
    const int rbase = hl << 2;
#pragma unroll
    for (int i = 0; i < 4; ++i) {
#pragma unroll
        for (int j = 0; j < 2; ++j) {
            int* p = C + (size_t)(row0 + wm + i * 32) * N_DIM
                       + (col0 + wn + j * 32 + ccol);
#pragma unroll
            for (int r = 0; r < 16; ++r) {
                int row = (r & 3) + 8 * (r >> 2) + rbase;
                int v = acc[i][j][r];
                p[(size_t)row * N_DIM] = v;
                int a = v < 0 ? -v : v;
                mymax = a > mymax ? a : mymax;
            }
        }
    }

    // wave-reduce max, then one atomic per block
#pragma unroll
    for (int off = 32; off > 0; off >>= 1) {
        int o = __shfl_down(mymax, off, 64);
        mymax = o > mymax ? o : mymax;
    }
    if (lane == 0) wmaxs[wave] = mymax;
    __syncthreads();
    if (tid == 0) {
        int bmx = wmaxs[0];
        for (int w = 1; w < 4; ++w) bmx = wmaxs[w] > bmx ? wmaxs[w] : bmx;
        atomicMax(maxabs, bmx);
    }
}

// ---------------------------------------------------------------------------
// Pseudo-stochastic shift, faithful to PstoShiftInt32 (all-integer, exact).
// Returns the int8 result sign-extended to int32.
// ---------------------------------------------------------------------------
__device__ __forceinline__ int psto(int x, int eff) {
    if (eff > 0) {
        int rt   = x >> eff;                 // floor divide by 2^eff
        int prob = x & ((1 << eff) - 1);     // non-negative floor remainder
        int h    = eff >> 1;
        int qp   = prob >> h;
        int prn  = (prob & ((1 << h) - 1)) << (eff & 1);
        int sgn  = (x > 0) - (x < 0);
        int r    = rt + ((qp <= prn) ? 0 : sgn);
        r = r < -127 ? -127 : r;
        r = r > 127 ? 127 : r;
        return r;
    }
    return (int)(int8_t)x;                   // wrapping int8 cast, as in torch
}

// ---------------------------------------------------------------------------
// In-place: read int32 acc from C, write int32 quantized value back.
// 8 elements (two int4) per thread. d_out is an int32 buffer.
// ---------------------------------------------------------------------------
__global__ __launch_bounds__(256) void finalize_kernel(int* __restrict__ C,
        const int* __restrict__ maxabs,
        const int* __restrict__ exp_in,
        const int* __restrict__ wexp) {
    const int m = *maxabs;
    int bw = 0;
    if (m != 0) bw = (int)ceilf(log2f((float)m));   // float32 path, as reference
    const int shift = bw - BITWIDTH;
    const int eff = (shift > 1) ? shift : ((shift == 1) ? 2 : 0);

    const size_t idx = ((size_t)blockIdx.x * blockDim.x + threadIdx.x) * 8;
    int4 v0 = *(const int4*)(C + idx);
    int4 v1 = *(const int4*)(C + idx + 4);
    int4 o0, o1;
    o0.x = psto(v0.x, eff); o0.y = psto(v0.y, eff);
    o0.z = psto(v0.z, eff); o0.w = psto(v0.w, eff);
    o1.x = psto(v1.x, eff); o1.y = psto(v1.y, eff);
    o1.z = psto(v1.z, eff); o1.w = psto(v1.w, eff);
    *(int4*)(C + idx) = o0;
    *(int4*)(C + idx + 4) = o1;

    if (idx == 0) {
        C[(size_t)M_DIM * N_DIM] = (int)(int8_t)(exp_in[0] + wexp[0] + eff);
    }
}

// ---------------------------------------------------------------------------
extern "C" void kernel_launch(void* const* d_in, const int* in_sizes, int n_in,
                              void* d_out, int out_size, void* d_ws, size_t ws_size,
                              hipStream_t stream) {
    const int* act    = (const int*)d_in[0];
    const int* exp_in = (const int*)d_in[1];
    const int* wt     = (const int*)d_in[2];
    const int* wexp   = (const int*)d_in[3];

    int8_t* a8p    = (int8_t*)d_ws;                          // 32 MB (frag-packed)
    int8_t* w8     = a8p + (size_t)M_DIM * K_DIM;            // 16 MB
    int*    maxabs = (int*)(w8 + (size_t)N_DIM * K_DIM);     // 4 B

    // blocks [0,8192): A frag-pack; [8192,16384): B row-major pack
    pack_both_kernel<<<16384, 256, 0, stream>>>(
        act, wt, (uint32_t*)a8p, (uint32_t*)w8, maxabs);

    int* C = (int*)d_out;    // acc staged in-place in d_out
    dim3 grid(N_DIM / BN, M_DIM / BM);
    gemm_i8<<<grid, 256, 0, stream>>>(a8p, w8, C, maxabs);

    finalize_kernel<<<((size_t)M_DIM * N_DIM / 8) / 256, 256, 0, stream>>>(
        C, maxabs, exp_in, wexp);
}

// Round 6
// 440.118 us; speedup vs baseline: 1.3285x; 1.0249x over previous
//
#include <hip/hip_runtime.h>
#include <stdint.h>
#include <math.h>

#define M_DIM 8192
#define N_DIM 4096
#define K_DIM 4096
#define BITWIDTH 7

#define BM 256
#define BN 128
#define BK 128   // bytes of K per tile (row stride in LDS for B)
#define NT (K_DIM / BK)   // 32 K-tiles

using i32x4  = __attribute__((ext_vector_type(4)))  int;
using i32x16 = __attribute__((ext_vector_type(16))) int;

#define FENCE asm volatile("" ::: "memory")

// ---------------------------------------------------------------------------
// Combined pack, one launch:
//   blocks [0, 8192):    A -> MFMA-fragment-blocked int8 layout
//   blocks [8192,16384): B -> row-major int8 (unchanged path)
//
// A packed layout (R4-verified): for M-block mb (32 rows), K-block kb
// (32 bytes), a 1 KB block at ((mb*128 + kb) * 1024); lane L's 16 fragment
// bytes at offset L*16: A[mb*32 + (L&31)][kb*32 + (L>>5)*16 + 0..15].
// Byte-identical to the LDS image the verified fragment reads consumed,
// so gemm A-loads are coalesced global_load_dwordx4 (lane L at base+L*16).
// ---------------------------------------------------------------------------
__global__ __launch_bounds__(256) void pack_both_kernel(
        const int* __restrict__ act, const int* __restrict__ wt,
        uint32_t* __restrict__ a8p, uint32_t* __restrict__ w8,
        int* __restrict__ maxabs) {
    if (blockIdx.x == 0 && threadIdx.x == 0) *maxabs = 0;

    if (blockIdx.x < 8192) {
        // ---- A fragment pack: 2,097,152 threads, 16B out each ----
        const int tid = blockIdx.x * 256 + threadIdx.x;
        const int L  = tid & 63;
        const int kb = (tid >> 6) & 127;          // K/32 = 128 blocks
        const int mb = tid >> 13;                 // M/32 = 256 blocks
        const size_t src = (size_t)(mb * 32 + (L & 31)) * K_DIM
                         + kb * 32 + (L >> 5) * 16;
        const int4* s = (const int4*)(act + src);
        uint32_t w[4];
#pragma unroll
        for (int q = 0; q < 4; ++q) {
            int4 v = s[q];
            w[q] = (uint32_t)(v.x & 0xFF) | ((uint32_t)(v.y & 0xFF) << 8)
                 | ((uint32_t)(v.z & 0xFF) << 16) | ((uint32_t)(v.w & 0xFF) << 24);
        }
        ((uint4*)a8p)[tid] = make_uint4(w[0], w[1], w[2], w[3]);
    } else {
        // ---- B row-major pack: 8 int32 -> 8 bytes per thread ----
        const int i = (blockIdx.x - 8192) * 256 + threadIdx.x;
        int4 a = ((const int4*)wt)[2 * i];
        int4 b = ((const int4*)wt)[2 * i + 1];
        uint32_t p0 = (uint32_t)(a.x & 0xFF) | ((uint32_t)(a.y & 0xFF) << 8)
                    | ((uint32_t)(a.z & 0xFF) << 16) | ((uint32_t)(a.w & 0xFF) << 24);
        uint32_t p1 = (uint32_t)(b.x & 0xFF) | ((uint32_t)(b.y & 0xFF) << 8)
                    | ((uint32_t)(b.z & 0xFF) << 16) | ((uint32_t)(b.w & 0xFF) << 24);
        ((uint2*)w8)[i] = make_uint2(p0, p1);
    }
}

// ---------------------------------------------------------------------------
// async global->LDS, 16B per lane, LDS dest = wave-uniform base + lane*16
// ---------------------------------------------------------------------------
__device__ __forceinline__ void gload_lds16(const int8_t* g, int8_t* lds) {
    __builtin_amdgcn_global_load_lds(
        (__attribute__((address_space(1))) void*)g,
        (__attribute__((address_space(3))) void*)lds,
        16, 0, 0);
}

// load one kk-step's 4 A fragments (coalesced dwordx4 from packed layout)
__device__ __forceinline__ void load_af(i32x4 (&d)[4], const int8_t* aBase,
                                        int tkk) {
#pragma unroll
    for (int i = 0; i < 4; ++i)
        d[i] = *(const i32x4*)(aBase + (size_t)((i * 128 + tkk) << 10));
}

// one kk-step: 2 B-fragment ds_reads + 8 MFMAs
__device__ __forceinline__ void kkstep(const i32x4 (&a)[4], const int8_t* bbuf,
                                       const int (&bo)[2], i32x16 (&acc)[4][2]) {
    i32x4 b0 = *(const i32x4*)(bbuf + bo[0]);
    i32x4 b1 = *(const i32x4*)(bbuf + bo[1]);
#pragma unroll
    for (int i = 0; i < 4; ++i) {
        acc[i][0] = __builtin_amdgcn_mfma_i32_32x32x32_i8(a[i], b0, acc[i][0], 0, 0, 0);
        acc[i][1] = __builtin_amdgcn_mfma_i32_32x32x32_i8(a[i], b1, acc[i][1], 0, 0, 0);
    }
}

// ---------------------------------------------------------------------------
// i8 GEMM, R5 schedule: A from fragment-packed global with kk-level
// register double-buffer (afE/afO, static parity); B LDS double-buffered
// with raw s_barrier + counted vmcnt(4) (never 0 in the loop).
//
// Per tile t (steady state):
//   kk0: issue B(t+1) gload_lds x4 | issue af(t,1) | MFMA(af(t,0))
//   kk1: issue af(t,2)             | MFMA(af(t,1))
//   kk2: issue af(t,3)             | MFMA(af(t,2))
//   kk3: issue af(t+1,0)           | MFMA(af(t,3))
//   vmcnt(4)  -> retires B(t+1) (oldest; FENCEs pin issue order),
//                leaves af(t+1,0) in flight
//   s_barrier -> per-wave vmcnt before barrier = cross-wave LDS visibility
// A-load RAW protection is compiler dependency waits (plain C++ loads);
// each af set has ~8 MFMAs (~300-580 cyc) of cover vs ~200 cyc L1/L2.
// ---------------------------------------------------------------------------
__global__ __launch_bounds__(256, 2) void gemm_i8(
        const int8_t* __restrict__ A8p, const int8_t* __restrict__ B8,
        int* __restrict__ C, int* __restrict__ maxabs) {
    __shared__ __align__(16) int8_t Bs[2][BN * BK];   // 2 x 16 KB ring
    __shared__ int wmaxs[4];
    int8_t* BsF = &Bs[0][0];

    const int tid  = threadIdx.x;
    const int wave = tid >> 6;
    const int lane = tid & 63;
    const int fr   = lane & 31;
    const int hl   = lane >> 5;

    const int row0 = blockIdx.y * BM;
    const int col0 = blockIdx.x * BN;

    const int wm = (wave >> 1) * 128;  // wave row offset in block tile
    const int wn = (wave & 1) * 64;    // wave col offset

    i32x16 acc[4][2];
#pragma unroll
    for (int i = 0; i < 4; ++i)
#pragma unroll
        for (int j = 0; j < 2; ++j)
            acc[i][j] = (i32x16)(0);

    // --- B staging addressing (R0-verified) ---------------------------------
    // Round g (0..3), wave w, lane L: LDS row 32g + w*8 + (L>>3), slot L&7;
    // source chunk pre-swizzled (L&7)^(row&7). LDS dest linear.
    const int srowoff = lane >> 3;
    const int schk    = ((lane & 7) ^ srowoff) << 4;
    const int8_t* bg  = B8 + (size_t)(col0 + wave * 8 + srowoff) * K_DIM + schk;
    const int ldsoB   = wave * 1024;

    // --- A fragment addressing (packed global, coalesced) -------------------
    const int mbase = (row0 + wm) >> 5;
    const int8_t* aBase = A8p + (size_t)mbase * 128 * 1024 + (size_t)lane * 16;

    // --- B fragment LDS offsets (loop-invariant, R0-verified) ---------------
    const int swz = fr & 7;
    int boff[4][2];
#pragma unroll
    for (int kk = 0; kk < 4; ++kk) {
        const int co = (((kk * 2 + hl) ^ swz) << 4);
#pragma unroll
        for (int j = 0; j < 2; ++j)
            boff[kk][j] = (wn + j * 32 + fr) * BK + co;
    }

    i32x4 afE[4], afO[4];

    // --- prologue: stage B(0) into buf 0; load af(0,0) ----------------------
#pragma unroll
    for (int g = 0; g < 4; ++g)
        gload_lds16(bg + (size_t)(32 * g) * K_DIM, BsF + ldsoB + g * 4096);
    FENCE;
    load_af(afE, aBase, 0);
    asm volatile("s_waitcnt vmcnt(4)" ::: "memory");   // B(0) done; af0 in flight
    __builtin_amdgcn_s_barrier();

    // --- main K loop (t = 0 .. NT-2) ----------------------------------------
    for (int t = 0; t < NT - 1; ++t) {
        const int8_t* bbuf = BsF + ((t & 1) << 14);
        int8_t* bstg = BsF + (((t + 1) & 1) << 14) + ldsoB;
        const int kg = (t + 1) * BK;
#pragma unroll
        for (int g = 0; g < 4; ++g)
            gload_lds16(bg + kg + (size_t)(32 * g) * K_DIM, bstg + g * 4096);
        FENCE;
        load_af(afO, aBase, t * 4 + 1); FENCE;
        kkstep(afE, bbuf, boff[0], acc);
        load_af(afE, aBase, t * 4 + 2); FENCE;
        kkstep(afO, bbuf, boff[1], acc);
        load_af(afO, aBase, t * 4 + 3); FENCE;
        kkstep(afE, bbuf, boff[2], acc);
        load_af(afE, aBase, t * 4 + 4); FENCE;   // = af(t+1, 0)
        kkstep(afO, bbuf, boff[3], acc);
        asm volatile("s_waitcnt vmcnt(4)" ::: "memory");  // retire B(t+1)
        __builtin_amdgcn_s_barrier();
    }

    // --- peeled last tile (no staging issues) -------------------------------
    {
        const int tl = NT - 1;
        const int8_t* bbuf = BsF + ((tl & 1) << 14);
        load_af(afO, aBase, tl * 4 + 1);
        kkstep(afE, bbuf, boff[0], acc);
        load_af(afE, aBase, tl * 4 + 2);
        kkstep(afO, bbuf, boff[1], acc);
        load_af(afO, aBase, tl * 4 + 3);
        kkstep(afE, bbuf, boff[2], acc);
        kkstep(afO, bbuf, boff[3], acc);
    }

    // epilogue: 32x32 C/D layout: col = lane&31,
    // row = (reg&3) + 8*(reg>>2) + 4*(lane>>5)   [m74/m101, dtype-independent]
    int mymax = 0;
    const int ccol = fr;
    const int rbase = hl << 2;
#pragma unroll
    for (int i = 0; i < 4; ++i) {
#pragma unroll
        for (int j = 0; j < 2; ++j) {
            int* p = C + (size_t)(row0 + wm + i * 32) * N_DIM
                       + (col0 + wn + j * 32 + ccol);
#pragma unroll
            for (int r = 0; r < 16; ++r) {
                int row = (r & 3) + 8 * (r >> 2) + rbase;
                int v = acc[i][j][r];
                p[(size_t)row * N_DIM] = v;
                int a = v < 0 ? -v : v;
                mymax = a > mymax ? a : mymax;
            }
        }
    }

    // wave-reduce max, then one atomic per block
#pragma unroll
    for (int off = 32; off > 0; off >>= 1) {
        int o = __shfl_down(mymax, off, 64);
        mymax = o > mymax ? o : mymax;
    }
    if (lane == 0) wmaxs[wave] = mymax;
    __syncthreads();
    if (tid == 0) {
        int bmx = wmaxs[0];
        for (int w = 1; w < 4; ++w) bmx = wmaxs[w] > bmx ? wmaxs[w] : bmx;
        atomicMax(maxabs, bmx);
    }
}

// ---------------------------------------------------------------------------
// Pseudo-stochastic shift, faithful to PstoShiftInt32 (all-integer, exact).
// Returns the int8 result sign-extended to int32.
// ---------------------------------------------------------------------------
__device__ __forceinline__ int psto(int x, int eff) {
    if (eff > 0) {
        int rt   = x >> eff;                 // floor divide by 2^eff
        int prob = x & ((1 << eff) - 1);     // non-negative floor remainder
        int h    = eff >> 1;
        int qp   = prob >> h;
        int prn  = (prob & ((1 << h) - 1)) << (eff & 1);
        int sgn  = (x > 0) - (x < 0);
        int r    = rt + ((qp <= prn) ? 0 : sgn);
        r = r < -127 ? -127 : r;
        r = r > 127 ? 127 : r;
        return r;
    }
    return (int)(int8_t)x;                   // wrapping int8 cast, as in torch
}

// ---------------------------------------------------------------------------
// In-place: read int32 acc from C, write int32 quantized value back.
// 8 elements (two int4) per thread. d_out is an int32 buffer.
// ---------------------------------------------------------------------------
__global__ __launch_bounds__(256) void finalize_kernel(int* __restrict__ C,
        const int* __restrict__ maxabs,
        const int* __restrict__ exp_in,
        const int* __restrict__ wexp) {
    const int m = *maxabs;
    int bw = 0;
    if (m != 0) bw = (int)ceilf(log2f((float)m));   // float32 path, as reference
    const int shift = bw - BITWIDTH;
    const int eff = (shift > 1) ? shift : ((shift == 1) ? 2 : 0);

    const size_t idx = ((size_t)blockIdx.x * blockDim.x + threadIdx.x) * 8;
    int4 v0 = *(const int4*)(C + idx);
    int4 v1 = *(const int4*)(C + idx + 4);
    int4 o0, o1;
    o0.x = psto(v0.x, eff); o0.y = psto(v0.y, eff);
    o0.z = psto(v0.z, eff); o0.w = psto(v0.w, eff);
    o1.x = psto(v1.x, eff); o1.y = psto(v1.y, eff);
    o1.z = psto(v1.z, eff); o1.w = psto(v1.w, eff);
    *(int4*)(C + idx) = o0;
    *(int4*)(C + idx + 4) = o1;

    if (idx == 0) {
        C[(size_t)M_DIM * N_DIM] = (int)(int8_t)(exp_in[0] + wexp[0] + eff);
    }
}

// ---------------------------------------------------------------------------
extern "C" void kernel_launch(void* const* d_in, const int* in_sizes, int n_in,
                              void* d_out, int out_size, void* d_ws, size_t ws_size,
                              hipStream_t stream) {
    const int* act    = (const int*)d_in[0];
    const int* exp_in = (const int*)d_in[1];
    const int* wt     = (const int*)d_in[2];
    const int* wexp   = (const int*)d_in[3];

    int8_t* a8p    = (int8_t*)d_ws;                          // 32 MB (frag-packed)
    int8_t* w8     = a8p + (size_t)M_DIM * K_DIM;            // 16 MB
    int*    maxabs = (int*)(w8 + (size_t)N_DIM * K_DIM);     // 4 B

    // blocks [0,8192): A frag-pack; [8192,16384): B row-major pack
    pack_both_kernel<<<16384, 256, 0, stream>>>(
        act, wt, (uint32_t*)a8p, (uint32_t*)w8, maxabs);

    int* C = (int*)d_out;    // acc staged in-place in d_out
    dim3 grid(N_DIM / BN, M_DIM / BM);
    gemm_i8<<<grid, 256, 0, stream>>>(a8p, w8, C, maxabs);

    finalize_kernel<<<((size_t)M_DIM * N_DIM / 8) / 256, 256, 0, stream>>>(
        C, maxabs, exp_in, wexp);
}

// Round 7
// 434.199 us; speedup vs baseline: 1.3466x; 1.0136x over previous
//
#include <hip/hip_runtime.h>
#include <stdint.h>
#include <math.h>

#define M_DIM 8192
#define N_DIM 4096
#define K_DIM 4096
#define BITWIDTH 7

#define BM 256
#define BN 128
#define BK 128   // bytes of K per tile (row stride in LDS for B)
#define NT (K_DIM / BK)   // 32 K-tiles

using i32x4  = __attribute__((ext_vector_type(4)))  int;
using i32x16 = __attribute__((ext_vector_type(16))) int;

#define FENCE asm volatile("" ::: "memory")

// ---------------------------------------------------------------------------
// Combined pack, one launch:
//   blocks [0, 8192):    A -> MFMA-fragment-blocked int8 layout
//   blocks [8192,16384): B -> row-major int8 (unchanged path)
//
// A packed layout (R4-verified): for M-block mb (32 rows), K-block kb
// (32 bytes), a 1 KB block at ((mb*128 + kb) * 1024); lane L's 16 fragment
// bytes at offset L*16: A[mb*32 + (L&31)][kb*32 + (L>>5)*16 + 0..15].
// Byte-identical to the LDS image the verified fragment reads consumed,
// so gemm A-loads are coalesced global_load_dwordx4 (lane L at base+L*16).
// ---------------------------------------------------------------------------
__global__ __launch_bounds__(256) void pack_both_kernel(
        const int* __restrict__ act, const int* __restrict__ wt,
        uint32_t* __restrict__ a8p, uint32_t* __restrict__ w8,
        int* __restrict__ maxabs) {
    if (blockIdx.x == 0 && threadIdx.x == 0) *maxabs = 0;

    if (blockIdx.x < 8192) {
        // ---- A fragment pack: 2,097,152 threads, 16B out each ----
        const int tid = blockIdx.x * 256 + threadIdx.x;
        const int L  = tid & 63;
        const int kb = (tid >> 6) & 127;          // K/32 = 128 blocks
        const int mb = tid >> 13;                 // M/32 = 256 blocks
        const size_t src = (size_t)(mb * 32 + (L & 31)) * K_DIM
                         + kb * 32 + (L >> 5) * 16;
        const int4* s = (const int4*)(act + src);
        uint32_t w[4];
#pragma unroll
        for (int q = 0; q < 4; ++q) {
            int4 v = s[q];
            w[q] = (uint32_t)(v.x & 0xFF) | ((uint32_t)(v.y & 0xFF) << 8)
                 | ((uint32_t)(v.z & 0xFF) << 16) | ((uint32_t)(v.w & 0xFF) << 24);
        }
        ((uint4*)a8p)[tid] = make_uint4(w[0], w[1], w[2], w[3]);
    } else {
        // ---- B row-major pack: 8 int32 -> 8 bytes per thread ----
        const int i = (blockIdx.x - 8192) * 256 + threadIdx.x;
        int4 a = ((const int4*)wt)[2 * i];
        int4 b = ((const int4*)wt)[2 * i + 1];
        uint32_t p0 = (uint32_t)(a.x & 0xFF) | ((uint32_t)(a.y & 0xFF) << 8)
                    | ((uint32_t)(a.z & 0xFF) << 16) | ((uint32_t)(a.w & 0xFF) << 24);
        uint32_t p1 = (uint32_t)(b.x & 0xFF) | ((uint32_t)(b.y & 0xFF) << 8)
                    | ((uint32_t)(b.z & 0xFF) << 16) | ((uint32_t)(b.w & 0xFF) << 24);
        ((uint2*)w8)[i] = make_uint2(p0, p1);
    }
}

// ---------------------------------------------------------------------------
// async global->LDS, 16B per lane, LDS dest = wave-uniform base + lane*16
// ---------------------------------------------------------------------------
__device__ __forceinline__ void gload_lds16(const int8_t* g, int8_t* lds) {
    __builtin_amdgcn_global_load_lds(
        (__attribute__((address_space(1))) void*)g,
        (__attribute__((address_space(3))) void*)lds,
        16, 0, 0);
}

// load one kk-step's 2 A fragments (coalesced dwordx4 from packed layout)
__device__ __forceinline__ void load_af(i32x4 (&d)[2], const int8_t* aBase,
                                        int tkk) {
#pragma unroll
    for (int i = 0; i < 2; ++i)
        d[i] = *(const i32x4*)(aBase + (size_t)((i * 128 + tkk) << 10));
}

// load one kk-step's 4 B fragments from LDS (swizzled chunk offset co)
__device__ __forceinline__ void load_bf(i32x4 (&d)[4], const int8_t* bbuf,
                                        const int (&ro)[4], int co) {
#pragma unroll
    for (int j = 0; j < 4; ++j)
        d[j] = *(const i32x4*)(bbuf + ro[j] + co);
}

// one kk-step: 8 MFMAs, all operands pre-loaded (no memory ops inside)
__device__ __forceinline__ void kkstep(const i32x4 (&a)[2], const i32x4 (&b)[4],
                                       i32x16 (&acc)[2][4]) {
#pragma unroll
    for (int i = 0; i < 2; ++i)
#pragma unroll
        for (int j = 0; j < 4; ++j)
            acc[i][j] = __builtin_amdgcn_mfma_i32_32x32x32_i8(
                a[i], b[j], acc[i][j], 0, 0, 0);
}

// ---------------------------------------------------------------------------
// i8 GEMM, R6 schedule.
//
// Wave grid 4Mx1N (wave tile 64x128): each wave owns DISTINCT A rows
// (fixes R5's 2x redundant A-from-L2 traffic: 2300 -> 1150 cyc/CU/tile,
// now well under the 2330-cyc MFMA floor). B fragments: each wave reads
// the full 128-col B tile (16 ds_read_b128/tile; LDS pipe ~2050 cyc/CU
// incl. staging writes, still < MFMA).
//
// Both operand classes register-double-buffered at kk granularity
// (static parity E/O, rule-#20-safe): every 8-MFMA cluster consumes
// fragments issued >= 1 kkstep (~300-600 cyc) earlier, so no dependent
// load wait sits directly in front of an MFMA cluster.
//
// In-order vmcnt audit (per tile t): issue order
//   [bf(t,0) ds] [af(t,1)] [B(t+1) glds x4] [bf(t,1) ds] kk0
//   [af(t,2)] [bf(t,2) ds] kk1   <- af(t,1) wait leaves B in flight
//   [af(t,3)] [bf(t,3) ds] kk2   <- af(t,2) wait retires B (2 kksteps cover)
//   [af(t+1,0)]            kk3   <- af(t,3) wait keeps af(t+1,0) in flight
//   vmcnt(2)  s_barrier          <- af(t+1,0) survives the barrier
// ---------------------------------------------------------------------------
__global__ __launch_bounds__(256, 2) void gemm_i8(
        const int8_t* __restrict__ A8p, const int8_t* __restrict__ B8,
        int* __restrict__ C, int* __restrict__ maxabs) {
    __shared__ __align__(16) int8_t Bs[2][BN * BK];   // 2 x 16 KB ring
    __shared__ int wmaxs[4];
    int8_t* BsF = &Bs[0][0];

    const int tid  = threadIdx.x;
    const int wave = tid >> 6;
    const int lane = tid & 63;
    const int fr   = lane & 31;
    const int hl   = lane >> 5;

    const int row0 = blockIdx.y * BM;
    const int col0 = blockIdx.x * BN;

    const int wm = wave * 64;          // wave row offset (4M x 1N grid)

    i32x16 acc[2][4];
#pragma unroll
    for (int i = 0; i < 2; ++i)
#pragma unroll
        for (int j = 0; j < 4; ++j)
            acc[i][j] = (i32x16)(0);

    // --- B staging addressing (R0-verified) ---------------------------------
    // Round g (0..3), wave w, lane L: LDS row 32g + w*8 + (L>>3), slot L&7;
    // source chunk pre-swizzled (L&7)^(row&7). LDS dest linear.
    const int srowoff = lane >> 3;
    const int schk    = ((lane & 7) ^ srowoff) << 4;
    const int8_t* bg  = B8 + (size_t)(col0 + wave * 8 + srowoff) * K_DIM + schk;
    const int ldsoB   = wave * 1024;

    // --- A fragment addressing (packed global, coalesced, deduped) ----------
    const int mbase = (row0 >> 5) + wave * 2;
    const int8_t* aBase = A8p + ((size_t)mbase << 17) + (size_t)lane * 16;

    // --- B fragment LDS offsets: row term + per-kk swizzled chunk term ------
    // B frag row = j*32 + fr, chunk c = kk*2 + hl, slot = c ^ (fr&7).
    const int swz = fr & 7;
    int rowOff[4];
#pragma unroll
    for (int j = 0; j < 4; ++j)
        rowOff[j] = (j * 32 + fr) * BK;
    int co[4];
#pragma unroll
    for (int kk = 0; kk < 4; ++kk)
        co[kk] = ((kk * 2 + hl) ^ swz) << 4;

    i32x4 afE[2], afO[2], bfE[4], bfO[4];

    // --- prologue: stage B(0) into buf 0; prefetch af(0,0) ------------------
#pragma unroll
    for (int g = 0; g < 4; ++g)
        gload_lds16(bg + (size_t)(32 * g) * K_DIM, BsF + ldsoB + g * 4096);
    FENCE;
    load_af(afE, aBase, 0);
    asm volatile("s_waitcnt vmcnt(2)" ::: "memory");   // B(0) landed; afE flying
    __builtin_amdgcn_s_barrier();

    // --- main K loop (t = 0 .. NT-2) ----------------------------------------
    for (int t = 0; t < NT - 1; ++t) {
        const int8_t* bbuf = BsF + ((t & 1) << 14);
        int8_t* bstg = BsF + (((t + 1) & 1) << 14) + ldsoB;
        const int kg = (t + 1) * BK;

        load_bf(bfE, bbuf, rowOff, co[0]); FENCE;          // bf(t,0)
        load_af(afO, aBase, t * 4 + 1);    FENCE;          // af(t,1)
#pragma unroll
        for (int g = 0; g < 4; ++g)
            gload_lds16(bg + kg + (size_t)(32 * g) * K_DIM, bstg + g * 4096);
        FENCE;
        load_bf(bfO, bbuf, rowOff, co[1]); FENCE;          // bf(t,1)
        kkstep(afE, bfE, acc);                             // kk0
        load_af(afE, aBase, t * 4 + 2);
        load_bf(bfE, bbuf, rowOff, co[2]); FENCE;          // af/bf(t,2)
        kkstep(afO, bfO, acc);                             // kk1
        load_af(afO, aBase, t * 4 + 3);
        load_bf(bfO, bbuf, rowOff, co[3]); FENCE;          // af/bf(t,3)
        kkstep(afE, bfE, acc);                             // kk2 (retires B glds)
        load_af(afE, aBase, t * 4 + 4);    FENCE;          // af(t+1,0)
        kkstep(afO, bfO, acc);                             // kk3
        asm volatile("s_waitcnt vmcnt(2)" ::: "memory");   // B(t+1) retired
        __builtin_amdgcn_s_barrier();
    }

    // --- peeled last tile (no staging, no next-tile prefetch) ---------------
    {
        const int tl = NT - 1;
        const int8_t* bbuf = BsF + ((tl & 1) << 14);
        load_bf(bfE, bbuf, rowOff, co[0]);
        load_af(afO, aBase, tl * 4 + 1);
        load_bf(bfO, bbuf, rowOff, co[1]); FENCE;
        kkstep(afE, bfE, acc);
        load_af(afE, aBase, tl * 4 + 2);
        load_bf(bfE, bbuf, rowOff, co[2]); FENCE;
        kkstep(afO, bfO, acc);
        load_af(afO, aBase, tl * 4 + 3);
        load_bf(bfO, bbuf, rowOff, co[3]); FENCE;
        kkstep(afE, bfE, acc);
        kkstep(afO, bfO, acc);
    }

    // epilogue: 32x32 C/D layout: col = lane&31,
    // row = (reg&3) + 8*(reg>>2) + 4*(lane>>5)   [m74/m101, dtype-independent]
    int mymax = 0;
    const int ccol = fr;
    const int rbase = hl << 2;
#pragma unroll
    for (int i = 0; i < 2; ++i) {
#pragma unroll
        for (int j = 0; j < 4; ++j) {
            int* p = C + (size_t)(row0 + wm + i * 32) * N_DIM
                       + (col0 + j * 32 + ccol);
#pragma unroll
            for (int r = 0; r < 16; ++r) {
                int row = (r & 3) + 8 * (r >> 2) + rbase;
                int v = acc[i][j][r];
                p[(size_t)row * N_DIM] = v;
                int a = v < 0 ? -v : v;
                mymax = a > mymax ? a : mymax;
            }
        }
    }

    // wave-reduce max, then one atomic per block
#pragma unroll
    for (int off = 32; off > 0; off >>= 1) {
        int o = __shfl_down(mymax, off, 64);
        mymax = o > mymax ? o : mymax;
    }
    if (lane == 0) wmaxs[wave] = mymax;
    __syncthreads();
    if (tid == 0) {
        int bmx = wmaxs[0];
        for (int w = 1; w < 4; ++w) bmx = wmaxs[w] > bmx ? wmaxs[w] : bmx;
        atomicMax(maxabs, bmx);
    }
}

// ---------------------------------------------------------------------------
// Pseudo-stochastic shift, faithful to PstoShiftInt32 (all-integer, exact).
// Returns the int8 result sign-extended to int32.
// ---------------------------------------------------------------------------
__device__ __forceinline__ int psto(int x, int eff) {
    if (eff > 0) {
        int rt   = x >> eff;                 // floor divide by 2^eff
        int prob = x & ((1 << eff) - 1);     // non-negative floor remainder
        int h    = eff >> 1;
        int qp   = prob >> h;
        int prn  = (prob & ((1 << h) - 1)) << (eff & 1);
        int sgn  = (x > 0) - (x < 0);
        int r    = rt + ((qp <= prn) ? 0 : sgn);
        r = r < -127 ? -127 : r;
        r = r > 127 ? 127 : r;
        return r;
    }
    return (int)(int8_t)x;                   // wrapping int8 cast, as in torch
}

// ---------------------------------------------------------------------------
// In-place: read int32 acc from C, write int32 quantized value back.
// 8 elements (two int4) per thread. d_out is an int32 buffer.
// ---------------------------------------------------------------------------
__global__ __launch_bounds__(256) void finalize_kernel(int* __restrict__ C,
        const int* __restrict__ maxabs,
        const int* __restrict__ exp_in,
        const int* __restrict__ wexp) {
    const int m = *maxabs;
    int bw = 0;
    if (m != 0) bw = (int)ceilf(log2f((float)m));   // float32 path, as reference
    const int shift = bw - BITWIDTH;
    const int eff = (shift > 1) ? shift : ((shift == 1) ? 2 : 0);

    const size_t idx = ((size_t)blockIdx.x * blockDim.x + threadIdx.x) * 8;
    int4 v0 = *(const int4*)(C + idx);
    int4 v1 = *(const int4*)(C + idx + 4);
    int4 o0, o1;
    o0.x = psto(v0.x, eff); o0.y = psto(v0.y, eff);
    o0.z = psto(v0.z, eff); o0.w = psto(v0.w, eff);
    o1.x = psto(v1.x, eff); o1.y = psto(v1.y, eff);
    o1.z = psto(v1.z, eff); o1.w = psto(v1.w, eff);
    *(int4*)(C + idx) = o0;
    *(int4*)(C + idx + 4) = o1;

    if (idx == 0) {
        C[(size_t)M_DIM * N_DIM] = (int)(int8_t)(exp_in[0] + wexp[0] + eff);
    }
}

// ---------------------------------------------------------------------------
extern "C" void kernel_launch(void* const* d_in, const int* in_sizes, int n_in,
                              void* d_out, int out_size, void* d_ws, size_t ws_size,
                              hipStream_t stream) {
    const int* act    = (const int*)d_in[0];
    const int* exp_in = (const int*)d_in[1];
    const int* wt     = (const int*)d_in[2];
    const int* wexp   = (const int*)d_in[3];

    int8_t* a8p    = (int8_t*)d_ws;                          // 32 MB (frag-packed)
    int8_t* w8     = a8p + (size_t)M_DIM * K_DIM;            // 16 MB
    int*    maxabs = (int*)(w8 + (size_t)N_DIM * K_DIM);     // 4 B

    // blocks [0,8192): A frag-pack; [8192,16384): B row-major pack
    pack_both_kernel<<<16384, 256, 0, stream>>>(
        act, wt, (uint32_t*)a8p, (uint32_t*)w8, maxabs);

    int* C = (int*)d_out;    // acc staged in-place in d_out
    dim3 grid(N_DIM / BN, M_DIM / BM);
    gemm_i8<<<grid, 256, 0, stream>>>(a8p, w8, C, maxabs);

    finalize_kernel<<<((size_t)M_DIM * N_DIM / 8) / 256, 256, 0, stream>>>(
        C, maxabs, exp_in, wexp);
}